// Round 9
// baseline (261.705 us; speedup 1.0000x reference)
//
#include <hip/hip_runtime.h>
#include <stdint.h>

#define N_ROWS 32768
#define DIM    256
#define KCODES 8192
#define KSPLIT 4
#define KPS    (KCODES / KSPLIT)   /* 2048 codes per split */
#define BM     128                 /* rows per block = 4 waves x 32 */
#define NT     (KPS / 16)          /* 128 tiles of 16 codes */
#define THREADS 256

typedef int   v8i __attribute__((ext_vector_type(8)));
typedef float v4f __attribute__((ext_vector_type(4)));

// ------- Kernel A: w -> fp8(-w*2^13), bp = (1 + sum(w^2)) * 4096 -------------
__global__ void kconv(const float* __restrict__ wgt, uint32_t* __restrict__ wb8,
                      float* __restrict__ bp) {
  const int code = blockIdx.x * 4 + (threadIdx.x >> 6);
  const int l = threadIdx.x & 63;
  float4 v = *(const float4*)(wgt + (size_t)code * DIM + l * 4);
  float s = v.x * v.x + v.y * v.y + v.z * v.z + v.w * v.w;
  int u = __builtin_amdgcn_cvt_pk_fp8_f32(v.x * -8192.f, v.y * -8192.f, 0, false);
  u = __builtin_amdgcn_cvt_pk_fp8_f32(v.z * -8192.f, v.w * -8192.f, u, true);
  wb8[(size_t)code * 64 + l] = (uint32_t)u;
  for (int o = 32; o; o >>= 1) s += __shfl_down(s, o, 64);
  if (l == 0) bp[code] = (1.0f + s) * 4096.f;
}

// ---------------- Kernel B: register-streamed fp8 MFMA argmin ----------------
// No LDS / no barriers in the main loop: B tiles stream L2->regs, A resident
// in regs, bp in MFMA C-operand, argmin via mantissa-noise OR + min_u32.
__global__ __launch_bounds__(THREADS, 4) void kmain(
    const float* __restrict__ x, const uint32_t* __restrict__ wb8,
    const float* __restrict__ bp, uint64_t* __restrict__ cand) {
  __shared__ __align__(16) uint32_t sm32[8192];  // 32KB: prologue bounce + park
  const int rb = blockIdx.x * BM;
  const int sp = blockIdx.y;
  const int k0 = sp * KPS;
  const int t = threadIdx.x;
  const int wv = t >> 6, l = t & 63;
  const int col = l & 15, kq = l >> 4;

  // ---- prologue: own 32 rows fp32 -> fp8 -> LDS (32B-swizzled) -> regs ----
#pragma unroll 4
  for (int i = 0; i < 32; ++i) {
    const float4 xv = *(const float4*)(x + (size_t)(rb + wv * 32 + i) * DIM + l * 4);
    int u = __builtin_amdgcn_cvt_pk_fp8_f32(xv.x, xv.y, 0, false);
    u = __builtin_amdgcn_cvt_pk_fp8_f32(xv.z, xv.w, u, true);
    sm32[wv * 2048 + i * 64 + (((l >> 3) ^ (i & 7)) << 3) + (l & 7)] = u;
  }
  v8i a00, a01, a10, a11;
  {
    const int r0 = col, r1 = 16 + col;
    const uint32_t* b0 = sm32 + wv * 2048 + r0 * 64;
    const uint32_t* b1 = sm32 + wv * 2048 + r1 * 64;
    a00 = *(const v8i*)(b0 + (((kq) ^ (r0 & 7)) << 3));
    a01 = *(const v8i*)(b0 + (((4 + kq) ^ (r0 & 7)) << 3));
    a10 = *(const v8i*)(b1 + (((kq) ^ (r1 & 7)) << 3));
    a11 = *(const v8i*)(b1 + (((4 + kq) ^ (r1 & 7)) << 3));
  }

  uint32_t mp[8];
#pragma unroll
  for (int j = 0; j < 8; ++j) mp[j] = 0xFFFFFFFFu;

  // lane-fixed B stream: code = k0 + tile*16 + col, k-window = kq*32 (+half*128)
  const uint32_t* bsrc = wb8 + ((size_t)(k0 + col) << 6) + (kq << 3);
  const float* bpp = bp + k0 + col;
  v8i c0 = *(const v8i*)(bsrc);
  v8i c1 = *(const v8i*)(bsrc + 32);
  float bv0 = *bpp;
  bsrc += 1024; bpp += 16;
  v8i n0, n1;
  float bv1;

  for (int tt = 0; tt < NT; tt += 2) {
    // body 1: prefetch tile tt+1, compute tile tt
    n0 = *(const v8i*)(bsrc);
    n1 = *(const v8i*)(bsrc + 32);
    bv1 = *bpp;
    bsrc += 1024; bpp += 16;
    {
      v4f acc0 = {bv0, bv0, bv0, bv0}, acc1 = {bv0, bv0, bv0, bv0};
      __builtin_amdgcn_s_setprio(1);
      acc0 = __builtin_amdgcn_mfma_scale_f32_16x16x128_f8f6f4(a00, c0, acc0, 0, 0, 0, 127, 0, 127);
      acc0 = __builtin_amdgcn_mfma_scale_f32_16x16x128_f8f6f4(a01, c1, acc0, 0, 0, 0, 127, 0, 127);
      acc1 = __builtin_amdgcn_mfma_scale_f32_16x16x128_f8f6f4(a10, c0, acc1, 0, 0, 0, 127, 0, 127);
      acc1 = __builtin_amdgcn_mfma_scale_f32_16x16x128_f8f6f4(a11, c1, acc1, 0, 0, 0, 127, 0, 127);
      __builtin_amdgcn_s_setprio(0);
      const uint32_t vs = (uint32_t)(((tt & 63) << 4) | col);
#pragma unroll
      for (int j = 0; j < 4; ++j) {
        uint32_t p0 = __float_as_uint(acc0[j]) | vs;
        mp[j] = p0 < mp[j] ? p0 : mp[j];
        uint32_t p1 = __float_as_uint(acc1[j]) | vs;
        mp[4 + j] = p1 < mp[4 + j] ? p1 : mp[4 + j];
      }
    }
    // body 2: prefetch tile tt+2 (last one dead, lands in bp slack), compute tt+1
    c0 = *(const v8i*)(bsrc);
    c1 = *(const v8i*)(bsrc + 32);
    bv0 = *bpp;
    bsrc += 1024; bpp += 16;
    {
      v4f acc0 = {bv1, bv1, bv1, bv1}, acc1 = {bv1, bv1, bv1, bv1};
      __builtin_amdgcn_s_setprio(1);
      acc0 = __builtin_amdgcn_mfma_scale_f32_16x16x128_f8f6f4(a00, n0, acc0, 0, 0, 0, 127, 0, 127);
      acc0 = __builtin_amdgcn_mfma_scale_f32_16x16x128_f8f6f4(a01, n1, acc0, 0, 0, 0, 127, 0, 127);
      acc1 = __builtin_amdgcn_mfma_scale_f32_16x16x128_f8f6f4(a10, n0, acc1, 0, 0, 0, 127, 0, 127);
      acc1 = __builtin_amdgcn_mfma_scale_f32_16x16x128_f8f6f4(a11, n1, acc1, 0, 0, 0, 127, 0, 127);
      __builtin_amdgcn_s_setprio(0);
      const uint32_t vs = (uint32_t)((((tt + 1) & 63) << 4) | col);
#pragma unroll
      for (int j = 0; j < 4; ++j) {
        uint32_t p0 = __float_as_uint(acc0[j]) | vs;
        mp[j] = p0 < mp[j] ? p0 : mp[j];
        uint32_t p1 = __float_as_uint(acc1[j]) | vs;
        mp[4 + j] = p1 < mp[4 + j] ? p1 : mp[4 + j];
      }
    }
    if (tt == 62) {  // end of chunk 0 (tiles 0..63): park winners, reset
#pragma unroll
      for (int j = 0; j < 8; ++j) {
        sm32[wv * 2048 + j * 64 + l] = mp[j];
        mp[j] = 0xFFFFFFFFu;
      }
    }
  }

  // ---- fold chunks, cross-lane argmin over 16 cols, write candidates ----
#pragma unroll
  for (int j = 0; j < 8; ++j) {
    uint32_t c0w = sm32[wv * 2048 + j * 64 + l];
    uint32_t c1w = mp[j];
    uint64_t P0 = ((uint64_t)c0w << 13) | (uint32_t)(k0 + (c0w & 1023u));
    uint64_t P1 = ((uint64_t)c1w << 13) | (uint32_t)(k0 + 1024 + (c1w & 1023u));
    uint64_t P = P1 < P0 ? P1 : P0;
#pragma unroll
    for (int o = 1; o < 16; o <<= 1) {
      uint32_t lo = (uint32_t)P, hi = (uint32_t)(P >> 32);
      uint32_t olo = __shfl_xor(lo, o, 64), ohi = __shfl_xor(hi, o, 64);
      uint64_t other = ((uint64_t)ohi << 32) | olo;
      P = other < P ? other : P;
    }
    if (col == 0) {
      int row = rb + wv * 32 + (j >> 2) * 16 + kq * 4 + (j & 3);
      cand[(size_t)row * KSPLIT + sp] = P;
    }
  }
}

// ---------------- Kernel C: combine splits, gather, out, loss partials -------
__global__ void kout(const float* __restrict__ x, const float* __restrict__ wgt,
                     const uint64_t* __restrict__ cand, float* __restrict__ out,
                     float* __restrict__ partial) {
  const int t = threadIdx.x;
  const int rb = blockIdx.x * 64;
  __shared__ int sk[64];
  __shared__ float red[4];
  if (t < 64) {
    const uint64_t* c = cand + (size_t)(rb + t) * KSPLIT;
    uint64_t P = c[0];
#pragma unroll
    for (int i = 1; i < KSPLIT; ++i) P = c[i] < P ? c[i] : P;
    sk[t] = (int)(P & 8191u);
  }
  __syncthreads();
  float acc = 0.f;
  for (int r = 0; r < 64; ++r) {
    int k = sk[r];
    float qv = wgt[(size_t)k * DIM + t];
    float xv = x[(size_t)(rb + r) * DIM + t];
    out[(size_t)(rb + r) * DIM + t] = qv;
    float d = xv - qv;
    acc = fmaf(d, d, acc);
  }
  for (int o = 32; o; o >>= 1) acc += __shfl_down(acc, o, 64);
  if ((t & 63) == 0) red[t >> 6] = acc;
  __syncthreads();
  if (t == 0) partial[blockIdx.x] = red[0] + red[1] + red[2] + red[3];
}

// ---------------- Kernel D: final loss ---------------------------------------
__global__ void kloss(const float* __restrict__ partial, float* __restrict__ lossout) {
  const int t = threadIdx.x;
  float s = partial[t] + partial[t + 256];
  for (int o = 32; o; o >>= 1) s += __shfl_down(s, o, 64);
  __shared__ float red[4];
  if ((t & 63) == 0) red[t >> 6] = s;
  __syncthreads();
  if (t == 0) lossout[0] = 1.5f * (red[0] + red[1] + red[2] + red[3]) /
                           (float)((size_t)N_ROWS * DIM);
}

extern "C" void kernel_launch(void* const* d_in, const int* in_sizes, int n_in,
                              void* d_out, int out_size, void* d_ws, size_t ws_size,
                              hipStream_t stream) {
  const float* x   = (const float*)d_in[0];
  const float* wgt = (const float*)d_in[1];
  float* out = (float*)d_out;
  uint8_t* ws = (uint8_t*)d_ws;
  uint32_t* wb8     = (uint32_t*)ws;                                    // 2 MB
  float*    bp      = (float*)(ws + (2u << 20));                        // 32 KB (+slack)
  uint64_t* cand    = (uint64_t*)(ws + (2u << 20) + (64u << 10));       // 1 MB
  float*    partial = (float*)(ws + (2u << 20) + (64u << 10) + (2u << 20)); // 2 KB

  kconv<<<KCODES / 4, 256, 0, stream>>>(wgt, wb8, bp);
  dim3 g(N_ROWS / BM, KSPLIT);
  kmain<<<g, THREADS, 0, stream>>>(x, wb8, bp, cand);
  kout<<<N_ROWS / 64, 256, 0, stream>>>(x, wgt, cand, out, partial);
  kloss<<<1, 256, 0, stream>>>(partial, out + (size_t)N_ROWS * DIM);
}

// Round 10
// 173.119 us; speedup vs baseline: 1.5117x; 1.5117x over previous
//
#include <hip/hip_runtime.h>
#include <stdint.h>

#define N_ROWS 32768
#define DIM    256
#define KCODES 8192
#define KSPLIT 8
#define KPS    (KCODES / KSPLIT)   /* 1024 codes per split */
#define BM     256                 /* 4 waves x 64 rows */
#define BN     64
#define NT     (KPS / BN)          /* 16 tiles */
#define THREADS 256

typedef int   v4i  __attribute__((ext_vector_type(4)));
typedef int   v8i  __attribute__((ext_vector_type(8)));
typedef float v4f  __attribute__((ext_vector_type(4)));

__device__ __forceinline__ void gload_lds16(const void* g, void* l) {
  __builtin_amdgcn_global_load_lds((const __attribute__((address_space(1))) uint32_t*)g,
                                   (__attribute__((address_space(3))) uint32_t*)l, 16, 0, 0);
}

// ---- Kernel A: w -> fp8(-w*2^13) in MFMA-FRAGMENT-MAJOR layout, bp scaled ---
// wb8 layout (bytes): tile(64 codes)*16384 + frag(cf*2+khalf)*2048
//                     + half*1024 + (kq*16 + col)*16
// so kmain's DMA is linear and its ds_read_b128 is identity (conflict-free).
__global__ void kconv(const float* __restrict__ wgt, uint32_t* __restrict__ wb8,
                      float* __restrict__ bp) {
  const int t = threadIdx.x;
  const int w = t >> 6, l = t & 63;
  const int c = blockIdx.x * 32 + w * 8 + (l >> 3);   // code
  const int kc = l & 7;                                // 32B k-chunk of this code
  const float* src = wgt + (size_t)c * DIM + kc * 32;
  uint32_t u[8];
  float s = 0.f;
#pragma unroll
  for (int j = 0; j < 8; ++j) {
    float4 v = *(const float4*)(src + j * 4);
    s = fmaf(v.x, v.x, fmaf(v.y, v.y, fmaf(v.z, v.z, fmaf(v.w, v.w, s))));
    int uu = __builtin_amdgcn_cvt_pk_fp8_f32(v.x * -8192.f, v.y * -8192.f, 0, false);
    uu = __builtin_amdgcn_cvt_pk_fp8_f32(v.z * -8192.f, v.w * -8192.f, uu, true);
    u[j] = (uint32_t)uu;
  }
  const int tt = c >> 6, cfl = (c >> 4) & 3, col = c & 15;
  const int kq = kc & 3, kh = kc >> 2;
  uint32_t* dst = wb8 + (size_t)tt * 4096 + (cfl * 2 + kh) * 512 + (kq * 16 + col) * 4;
  *(int4*)dst = make_int4(u[0], u[1], u[2], u[3]);          // half 0
  *(int4*)(dst + 256) = make_int4(u[4], u[5], u[6], u[7]);  // half 1 (+1KB)
  // bp = (1 + sum w^2) * 4096, reduced over the 8 k-chunk lanes
  s += __shfl_xor(s, 1, 64);
  s += __shfl_xor(s, 2, 64);
  s += __shfl_xor(s, 4, 64);
  if (kc == 0) bp[c] = (1.0f + s) * 4096.f;
}

// ---------------- Kernel B: fp8 MX-MFMA distance argmin ----------------------
// 4 waves x 64 register-resident rows; B tile 64 codes staged frag-major via
// DMA (linear), read as identity ds_read_b128; bp in MFMA C-operand; argmin
// tag = 10-bit code-in-split in mantissa noise bits.
__global__ __launch_bounds__(THREADS, 4) void kmain(
    const float* __restrict__ x, const uint32_t* __restrict__ wb8,
    const float* __restrict__ bp, uint64_t* __restrict__ cand) {
  __shared__ __align__(16) uint8_t sm[32768];    // 2 x 16KB B buffers / A bounce
  __shared__ __align__(16) float bpl[KPS];       // 4KB
  const int rb = blockIdx.x * BM;
  const int sp = blockIdx.y;
  const int k0 = sp * KPS;
  const int t = threadIdx.x;
  const int wv = t >> 6, l = t & 63;
  const int col = l & 15, q = l >> 4;

  // bp slice -> LDS (drained by the pre-loop vmcnt(0))
  gload_lds16(bp + k0 + wv * 256 + l * 4, (uint8_t*)bpl + wv * 1024);

  // ---- prologue: 64 own rows fp32 -> fp8 -> frag-major LDS bounce -> regs ---
  // per-wave-private 8KB slice; two passes of 32 rows; no barriers needed.
  v8i afr[4][2];
  uint8_t* slice = sm + wv * 8192;
  const int kq2 = (col >> 1) & 3, khw = col >> 3, hb = col & 1;
#pragma unroll
  for (int p = 0; p < 2; ++p) {
#pragma unroll
    for (int i = 0; i < 8; ++i) {
      int rl = i * 4 + q;                        // row in pass, 0..31
      const float* xs = x + (size_t)(rb + wv * 64 + p * 32 + rl) * DIM + col * 16;
      uint32_t u[4];
#pragma unroll
      for (int j = 0; j < 4; ++j) {
        float4 v = *(const float4*)(xs + j * 4);
        int uu = __builtin_amdgcn_cvt_pk_fp8_f32(v.x, v.y, 0, false);
        uu = __builtin_amdgcn_cvt_pk_fp8_f32(v.z, v.w, uu, true);
        u[j] = (uint32_t)uu;
      }
      *(int4*)(slice + ((rl >> 4) * 2 + khw) * 2048 + hb * 1024 +
               (kq2 * 16 + (rl & 15)) * 16) = make_int4(u[0], u[1], u[2], u[3]);
    }
#pragma unroll
    for (int rp = 0; rp < 2; ++rp)
#pragma unroll
      for (int kh = 0; kh < 2; ++kh) {
        const uint8_t* fb = slice + (rp * 2 + kh) * 2048 + l * 16;
        v8i f;
        *(v4i*)&f = *(const v4i*)fb;
        *((v4i*)&f + 1) = *(const v4i*)(fb + 1024);
        afr[p * 2 + rp][kh] = f;
      }
  }
  __syncthreads();                                // prologue LDS use complete

  uint32_t mp[4][4];
#pragma unroll
  for (int rf = 0; rf < 4; ++rf)
#pragma unroll
    for (int j = 0; j < 4; ++j) mp[rf][j] = 0xFFFFFFFFu;

  // B stage: 16KB tile = 8 frags; wave stages frags 2wv, 2wv+1 (linear DMA)
  auto stage = [&](int kt, int buf) {
    const uint32_t* src = wb8 + (size_t)(sp * NT + kt) * 4096 + wv * 1024 + l * 4;
    uint8_t* dst = sm + buf * 16384 + wv * 4096;
    gload_lds16(src, dst);
    gload_lds16(src + 512, dst + 2048);
  };

  stage(0, 0);
  __builtin_amdgcn_sched_barrier(0);
  asm volatile("s_waitcnt vmcnt(0)" ::: "memory");
  __builtin_amdgcn_s_barrier();
  __builtin_amdgcn_sched_barrier(0);

  for (int kt = 0; kt < NT; ++kt) {
    const int cur = kt & 1;
    if (kt + 1 < NT) stage(kt + 1, cur ^ 1);
    const uint8_t* sb = sm + cur * 16384;
#pragma unroll
    for (int cf = 0; cf < 4; ++cf) {
      const float bpv = bpl[kt * 64 + cf * 16 + col];
      const uint8_t* f0 = sb + cf * 4096 + l * 16;
      v8i b0, b1;
      *(v4i*)&b0 = *(const v4i*)f0;
      *((v4i*)&b0 + 1) = *(const v4i*)(f0 + 1024);
      *(v4i*)&b1 = *(const v4i*)(f0 + 2048);
      *((v4i*)&b1 + 1) = *(const v4i*)(f0 + 3072);
      const uint32_t tag = (uint32_t)(kt * 64 + cf * 16 + col);   // 10-bit code id
      __builtin_amdgcn_s_setprio(1);
#pragma unroll
      for (int rf = 0; rf < 4; ++rf) {
        v4f acc = {bpv, bpv, bpv, bpv};
        // acc = bp*4096 + dot(x, -8192*w) = 4096*(sqdist - |x|^2)
        acc = __builtin_amdgcn_mfma_scale_f32_16x16x128_f8f6f4(
            afr[rf][0], b0, acc, 0, 0, 0, 127, 0, 127);
        acc = __builtin_amdgcn_mfma_scale_f32_16x16x128_f8f6f4(
            afr[rf][1], b1, acc, 0, 0, 0, 127, 0, 127);
#pragma unroll
        for (int j = 0; j < 4; ++j) {
          uint32_t pv = __float_as_uint(acc[j]) | tag;
          mp[rf][j] = pv < mp[rf][j] ? pv : mp[rf][j];
        }
      }
      __builtin_amdgcn_s_setprio(0);
    }
    __builtin_amdgcn_sched_barrier(0);
    asm volatile("s_waitcnt vmcnt(0)" ::: "memory");
    __builtin_amdgcn_s_barrier();
    __builtin_amdgcn_sched_barrier(0);
  }

  // ---- cross-lane argmin over the 16 code-columns, write candidates ----
#pragma unroll
  for (int rf = 0; rf < 4; ++rf)
#pragma unroll
    for (int j = 0; j < 4; ++j) {
      uint32_t pv = mp[rf][j];
#pragma unroll
      for (int o = 1; o < 16; o <<= 1) {
        uint32_t ov = (uint32_t)__shfl_xor((int)pv, o, 64);
        pv = ov < pv ? ov : pv;
      }
      if (col == 0) {
        int row = rb + wv * 64 + rf * 16 + q * 4 + j;
        cand[(size_t)row * KSPLIT + sp] =
            ((uint64_t)pv << 13) | (uint32_t)(k0 + (pv & 1023u));
      }
    }
}

// ---------------- Kernel C: combine splits, gather, out, loss partials -------
__global__ void kout(const float* __restrict__ x, const float* __restrict__ wgt,
                     const uint64_t* __restrict__ cand, float* __restrict__ out,
                     float* __restrict__ partial) {
  const int t = threadIdx.x;
  const int rb = blockIdx.x * 64;
  __shared__ int sk[64];
  __shared__ float red[4];
  if (t < 64) {
    const uint64_t* c = cand + (size_t)(rb + t) * KSPLIT;
    uint64_t P = c[0];
#pragma unroll
    for (int i = 1; i < KSPLIT; ++i) P = c[i] < P ? c[i] : P;
    sk[t] = (int)(P & 8191u);
  }
  __syncthreads();
  float acc = 0.f;
  for (int r = 0; r < 64; ++r) {
    int k = sk[r];
    float qv = wgt[(size_t)k * DIM + t];
    float xv = x[(size_t)(rb + r) * DIM + t];
    out[(size_t)(rb + r) * DIM + t] = qv;
    float d = xv - qv;
    acc = fmaf(d, d, acc);
  }
  for (int o = 32; o; o >>= 1) acc += __shfl_down(acc, o, 64);
  if ((t & 63) == 0) red[t >> 6] = acc;
  __syncthreads();
  if (t == 0) partial[blockIdx.x] = red[0] + red[1] + red[2] + red[3];
}

// ---------------- Kernel D: final loss ---------------------------------------
__global__ void kloss(const float* __restrict__ partial, float* __restrict__ lossout) {
  const int t = threadIdx.x;
  float s = partial[t] + partial[t + 256];
  for (int o = 32; o; o >>= 1) s += __shfl_down(s, o, 64);
  __shared__ float red[4];
  if ((t & 63) == 0) red[t >> 6] = s;
  __syncthreads();
  if (t == 0) lossout[0] = 1.5f * (red[0] + red[1] + red[2] + red[3]) /
                           (float)((size_t)N_ROWS * DIM);
}

extern "C" void kernel_launch(void* const* d_in, const int* in_sizes, int n_in,
                              void* d_out, int out_size, void* d_ws, size_t ws_size,
                              hipStream_t stream) {
  const float* x   = (const float*)d_in[0];
  const float* wgt = (const float*)d_in[1];
  float* out = (float*)d_out;
  uint8_t* ws = (uint8_t*)d_ws;
  uint32_t* wb8     = (uint32_t*)ws;                                    // 2 MB
  float*    bp      = (float*)(ws + (2u << 20));                        // 32 KB
  uint64_t* cand    = (uint64_t*)(ws + (2u << 20) + (64u << 10));       // 2 MB
  float*    partial = (float*)(ws + (2u << 20) + (64u << 10) + (2u << 20)); // 2 KB

  kconv<<<KCODES / 32, 256, 0, stream>>>(wgt, wb8, bp);
  dim3 g(N_ROWS / BM, KSPLIT);
  kmain<<<g, THREADS, 0, stream>>>(x, wb8, bp, cand);
  kout<<<N_ROWS / 64, 256, 0, stream>>>(x, wgt, cand, out, partial);
  kloss<<<1, 256, 0, stream>>>(partial, out + (size_t)N_ROWS * DIM);
}

// Round 11
// 92.596 us; speedup vs baseline: 2.8263x; 1.8696x over previous
//
#include <hip/hip_runtime.h>
#include <stdint.h>

#define N_ROWS 32768
#define DIM    256
#define KCODES 8192
#define KSPLIT 4
#define KPS    (KCODES / KSPLIT)   /* 2048 codes per split */
#define BM     128                 /* 4 waves x 32 rows */
#define BN     64
#define NT     (KPS / BN)          /* 32 tiles */
#define THREADS 256

typedef int   v4i  __attribute__((ext_vector_type(4)));
typedef int   v8i  __attribute__((ext_vector_type(8)));
typedef float v4f  __attribute__((ext_vector_type(4)));

__device__ __forceinline__ void gload_lds16(const void* g, void* l) {
  __builtin_amdgcn_global_load_lds((const __attribute__((address_space(1))) uint32_t*)g,
                                   (__attribute__((address_space(3))) uint32_t*)l, 16, 0, 0);
}

// ---- Kernel A: w -> fp8(-w*2^13) in MFMA-FRAGMENT-MAJOR layout, bp scaled ---
// wb8 u32 layout: tile(64 codes)*4096 + frag(cf*2+kh)*512 + plane(hb)*256
//                 + (kq*16 + col)*4   [identity for ds_read_b128 at lane*16]
__global__ void kconv(const float* __restrict__ wgt, uint32_t* __restrict__ wb8,
                      float* __restrict__ bp) {
  const int t = threadIdx.x;
  const int w = t >> 6, l = t & 63;
  const int c = blockIdx.x * 32 + w * 8 + (l >> 3);   // code
  const int kc = l & 7;                                // 32-fp8 k-chunk
  const float* src = wgt + (size_t)c * DIM + kc * 32;
  uint32_t u[8];
  float s = 0.f;
#pragma unroll
  for (int j = 0; j < 8; ++j) {
    float4 v = *(const float4*)(src + j * 4);
    s = fmaf(v.x, v.x, fmaf(v.y, v.y, fmaf(v.z, v.z, fmaf(v.w, v.w, s))));
    int uu = __builtin_amdgcn_cvt_pk_fp8_f32(v.x * -8192.f, v.y * -8192.f, 0, false);
    uu = __builtin_amdgcn_cvt_pk_fp8_f32(v.z * -8192.f, v.w * -8192.f, uu, true);
    u[j] = (uint32_t)uu;
  }
  const int tt = c >> 6, cfl = (c >> 4) & 3, col = c & 15;
  const int kq = kc & 3, kh = kc >> 2;
  uint32_t* dst = wb8 + (size_t)tt * 4096 + (cfl * 2 + kh) * 512 + (kq * 16 + col) * 4;
  *(int4*)dst = make_int4(u[0], u[1], u[2], u[3]);          // plane 0
  *(int4*)(dst + 256) = make_int4(u[4], u[5], u[6], u[7]);  // plane 1 (+1KB)
  s += __shfl_xor(s, 1, 64);
  s += __shfl_xor(s, 2, 64);
  s += __shfl_xor(s, 4, 64);
  if (kc == 0) bp[c] = (1.0f + s) * 4096.f;
}

// ---------------- Kernel B: fp8 MX-MFMA distance argmin ----------------------
// 4 waves x 32 rows; frag-major everywhere: linear DMA, identity ds_read_b128,
// 16x16x128 MFMA, bp in C-operand, 11-bit code tag in mantissa noise bits.
__global__ __launch_bounds__(THREADS, 4) void kmain(
    const float* __restrict__ x, const uint32_t* __restrict__ wb8,
    const float* __restrict__ bp, uint64_t* __restrict__ cand) {
  __shared__ __align__(16) uint8_t sm[32768];    // A bounce / 2 x 16KB B buffers
  __shared__ __align__(16) float bpl[KPS];       // 8KB
  const int rb = blockIdx.x * BM;
  const int sp = blockIdx.y;
  const int k0 = sp * KPS;
  const int t = threadIdx.x;
  const int wv = t >> 6, l = t & 63;
  const int col = l & 15, q = l >> 4;

  // bp slice (8KB) -> LDS: 2 gloads per wave; drained by pre-loop vmcnt(0)
  gload_lds16(bp + k0 + wv * 512 + l * 4, (uint8_t*)bpl + wv * 2048);
  gload_lds16(bp + k0 + wv * 512 + 256 + l * 4, (uint8_t*)bpl + wv * 2048 + 1024);

  // ---- prologue: 32 own rows fp32 -> fp8 -> frag-major LDS bounce -> regs ---
  v8i afr[2][2];
  {
    uint8_t* slice = sm + wv * 8192;
    const int kh = col >> 3, kq = (col >> 1) & 3, hb = col & 1;
#pragma unroll
    for (int i = 0; i < 8; ++i) {
      const int rl = i * 4 + q;                  // row in wave, 0..31
      const float* xs = x + (size_t)(rb + wv * 32 + rl) * DIM + col * 16;
      uint32_t u[4];
#pragma unroll
      for (int j = 0; j < 4; ++j) {
        float4 v = *(const float4*)(xs + j * 4);
        int uu = __builtin_amdgcn_cvt_pk_fp8_f32(v.x, v.y, 0, false);
        uu = __builtin_amdgcn_cvt_pk_fp8_f32(v.z, v.w, uu, true);
        u[j] = (uint32_t)uu;
      }
      *(int4*)(slice + ((rl >> 4) * 2 + kh) * 2048 + hb * 1024 +
               (kq * 16 + (rl & 15)) * 16) = make_int4(u[0], u[1], u[2], u[3]);
    }
#pragma unroll
    for (int rf = 0; rf < 2; ++rf)
#pragma unroll
      for (int kk = 0; kk < 2; ++kk) {
        const uint8_t* fb = slice + (rf * 2 + kk) * 2048 + l * 16;
        v8i f;
        *(v4i*)&f = *(const v4i*)fb;
        *((v4i*)&f + 1) = *(const v4i*)(fb + 1024);
        afr[rf][kk] = f;
      }
  }
  __syncthreads();                                // bounce done; sm -> B buffers

  uint32_t mp[2][4];
#pragma unroll
  for (int rf = 0; rf < 2; ++rf)
#pragma unroll
    for (int j = 0; j < 4; ++j) mp[rf][j] = 0xFFFFFFFFu;

  // B stage: 16KB tile, linear copy; wave stages its 4KB (frags 2wv, 2wv+1)
  auto stage = [&](int kt, int buf) {
    const uint32_t* src = wb8 + (size_t)(sp * NT + kt) * 4096 + wv * 1024 + l * 4;
    uint8_t* dst = sm + buf * 16384 + wv * 4096;
#pragma unroll
    for (int j = 0; j < 4; ++j)
      gload_lds16(src + j * 256, dst + j * 1024);
  };

  stage(0, 0);
  __builtin_amdgcn_sched_barrier(0);
  asm volatile("s_waitcnt vmcnt(0)" ::: "memory");
  __builtin_amdgcn_s_barrier();
  __builtin_amdgcn_sched_barrier(0);

  for (int kt = 0; kt < NT; ++kt) {
    const int cur = kt & 1;
    if (kt + 1 < NT) stage(kt + 1, cur ^ 1);
    const uint8_t* sb = sm + cur * 16384;
#pragma unroll
    for (int cf = 0; cf < 4; ++cf) {
      const float bpv = bpl[kt * 64 + cf * 16 + col];
      const uint8_t* fb = sb + cf * 4096 + l * 16;
      v8i b0, b1;
      *(v4i*)&b0 = *(const v4i*)fb;
      *((v4i*)&b0 + 1) = *(const v4i*)(fb + 1024);
      *(v4i*)&b1 = *(const v4i*)(fb + 2048);
      *((v4i*)&b1 + 1) = *(const v4i*)(fb + 3072);
      const uint32_t tag = (uint32_t)(kt * 64 + cf * 16 + col);   // 11-bit code id
      __builtin_amdgcn_s_setprio(1);
#pragma unroll
      for (int rf = 0; rf < 2; ++rf) {
        v4f acc = {bpv, bpv, bpv, bpv};
        // acc = bp*4096 + dot(x, -8192*w) = 4096*(sqdist - |x|^2)
        acc = __builtin_amdgcn_mfma_scale_f32_16x16x128_f8f6f4(
            afr[rf][0], b0, acc, 0, 0, 0, 127, 0, 127);
        acc = __builtin_amdgcn_mfma_scale_f32_16x16x128_f8f6f4(
            afr[rf][1], b1, acc, 0, 0, 0, 127, 0, 127);
#pragma unroll
        for (int j = 0; j < 4; ++j) {
          uint32_t pv = __float_as_uint(acc[j]) | tag;
          mp[rf][j] = pv < mp[rf][j] ? pv : mp[rf][j];
        }
      }
      __builtin_amdgcn_s_setprio(0);
    }
    __builtin_amdgcn_sched_barrier(0);
    asm volatile("s_waitcnt vmcnt(0)" ::: "memory");
    __builtin_amdgcn_s_barrier();
    __builtin_amdgcn_sched_barrier(0);
  }

  // ---- cross-lane argmin over the 16 code-columns, write candidates ----
#pragma unroll
  for (int rf = 0; rf < 2; ++rf)
#pragma unroll
    for (int j = 0; j < 4; ++j) {
      uint32_t pv = mp[rf][j];
#pragma unroll
      for (int o = 1; o < 16; o <<= 1) {
        uint32_t ov = (uint32_t)__shfl_xor((int)pv, o, 64);
        pv = ov < pv ? ov : pv;
      }
      if (col == 0) {
        int row = rb + wv * 32 + rf * 16 + q * 4 + j;
        cand[(size_t)row * KSPLIT + sp] =
            ((uint64_t)pv << 13) | (uint32_t)(k0 + (pv & 2047u));
      }
    }
}

// ---------------- Kernel C: combine splits, gather, out, loss partials -------
__global__ void kout(const float* __restrict__ x, const float* __restrict__ wgt,
                     const uint64_t* __restrict__ cand, float* __restrict__ out,
                     float* __restrict__ partial) {
  const int t = threadIdx.x;
  const int rb = blockIdx.x * 64;
  __shared__ int sk[64];
  __shared__ float red[4];
  if (t < 64) {
    const uint64_t* c = cand + (size_t)(rb + t) * KSPLIT;
    uint64_t P = c[0];
#pragma unroll
    for (int i = 1; i < KSPLIT; ++i) P = c[i] < P ? c[i] : P;
    sk[t] = (int)(P & 8191u);
  }
  __syncthreads();
  float acc = 0.f;
  for (int r = 0; r < 64; ++r) {
    int k = sk[r];
    float qv = wgt[(size_t)k * DIM + t];
    float xv = x[(size_t)(rb + r) * DIM + t];
    out[(size_t)(rb + r) * DIM + t] = qv;
    float d = xv - qv;
    acc = fmaf(d, d, acc);
  }
  for (int o = 32; o; o >>= 1) acc += __shfl_down(acc, o, 64);
  if ((t & 63) == 0) red[t >> 6] = acc;
  __syncthreads();
  if (t == 0) partial[blockIdx.x] = red[0] + red[1] + red[2] + red[3];
}

// ---------------- Kernel D: final loss ---------------------------------------
__global__ void kloss(const float* __restrict__ partial, float* __restrict__ lossout) {
  const int t = threadIdx.x;
  float s = partial[t] + partial[t + 256];
  for (int o = 32; o; o >>= 1) s += __shfl_down(s, o, 64);
  __shared__ float red[4];
  if ((t & 63) == 0) red[t >> 6] = s;
  __syncthreads();
  if (t == 0) lossout[0] = 1.5f * (red[0] + red[1] + red[2] + red[3]) /
                           (float)((size_t)N_ROWS * DIM);
}

extern "C" void kernel_launch(void* const* d_in, const int* in_sizes, int n_in,
                              void* d_out, int out_size, void* d_ws, size_t ws_size,
                              hipStream_t stream) {
  const float* x   = (const float*)d_in[0];
  const float* wgt = (const float*)d_in[1];
  float* out = (float*)d_out;
  uint8_t* ws = (uint8_t*)d_ws;
  uint32_t* wb8     = (uint32_t*)ws;                                    // 2 MB
  float*    bp      = (float*)(ws + (2u << 20));                        // 32 KB
  uint64_t* cand    = (uint64_t*)(ws + (2u << 20) + (64u << 10));       // 1 MB
  float*    partial = (float*)(ws + (2u << 20) + (64u << 10) + (2u << 20)); // 2 KB

  kconv<<<KCODES / 32, 256, 0, stream>>>(wgt, wb8, bp);
  dim3 g(N_ROWS / BM, KSPLIT);
  kmain<<<g, THREADS, 0, stream>>>(x, wb8, bp, cand);
  kout<<<N_ROWS / 64, 256, 0, stream>>>(x, wgt, cand, out, partial);
  kloss<<<1, 256, 0, stream>>>(partial, out + (size_t)N_ROWS * DIM);
}